// Round 2
// baseline (168.404 us; speedup 1.0000x reference)
//
#include <hip/hip_runtime.h>

// Problem constants (from reference): B=4096, N_ELEM=2048, N_NODES=1024, E2=4096
#define B_SAMPLES 4096
#define N_ELEM    2048
#define N_NODES   1024
#define E2        4096
#define BLOCK     256                    // setup kernels
#define MBLOCK    512                    // main kernel block
#define SLOTS     32                     // max entries/node (Poisson mean 4; P(>=32) ~ 1e-15)
#define S         4                      // samples per main block
#define MAIN_BLOCKS (B_SAMPLES / S)      // 1024

// Workspace layout (bytes):
//   [0, 4K)        : cnt[N_NODES]          (int)
//   [4K, 4K+512K)  : ell[SLOTS][N_NODES]   (float4 {wx, wy, bitcast(eid), pad})
//   [4K+512K, ...) : partial[MAIN_BLOCKS]  (float)
#define WS_CNT_OFF   0
#define WS_ELL_OFF   4096
#define WS_PART_OFF  (4096 + SLOTS * N_NODES * 16)

// ---------------------------------------------------------------------------
// Setup A: zero ELL table + counters. 128 blocks x 256 = one float4 each.
// ---------------------------------------------------------------------------
__global__ __launch_bounds__(BLOCK) void neq_zero_kernel(
    float4* __restrict__ ell, int* __restrict__ cnt)
{
    const int i = blockIdx.x * BLOCK + threadIdx.x;      // 0 .. 32767
    ell[i] = make_float4(0.f, 0.f, 0.f, 0.f);
    if (i < N_NODES) cnt[i] = 0;
}

// ---------------------------------------------------------------------------
// Setup B: build transposed-ELL via global atomics (order-independent sum).
// ---------------------------------------------------------------------------
__global__ __launch_bounds__(BLOCK) void neq_build_kernel(
    const float* __restrict__ vecs, const int* __restrict__ node_ids,
    const int* __restrict__ elem_ids, int* __restrict__ cnt,
    float4* __restrict__ ell)
{
    const int j = blockIdx.x * BLOCK + threadIdx.x;      // 0 .. E2-1
    int nid = node_ids[j];
    int eid = elem_ids[j];
    float2 v = ((const float2*)vecs)[j];
    int slot = atomicAdd(&cnt[nid], 1);                  // device-scope
    if (slot < SLOTS) {
        ell[slot * N_NODES + nid] = make_float4(v.x, v.y, __int_as_float(eid), 0.f);
    }
}

// FMA of a float4 (per-sample) by a scalar weight into a float4 accumulator.
#define FMA4(A, V, W) do { (A).x += (V).x * (W); (A).y += (V).y * (W); \
                           (A).z += (V).z * (W); (A).w += (V).w * (W); } while (0)

// ---------------------------------------------------------------------------
// Main: one block (512 threads) per S=4 samples.
// MLP-first structure: phase 1 uses float4 global loads + in-register 4x4
// transpose + ds_write_b128; phase 2 processes k in chunks of 2 rows x 2
// nodes (4 independent global loads + 4 independent LDS gathers in flight);
// phase 3 hoists all 16 q/r float2 loads.
// Zero-padded ELL rows make over-reading past kmax contribute exactly 0.
// ---------------------------------------------------------------------------
__global__ __launch_bounds__(MBLOCK, 8) void neq_main_kernel(
    const float* __restrict__ EA, const float* __restrict__ e,
    const float* __restrict__ q,  const float* __restrict__ r,
    const int* __restrict__ cnt, const float4* __restrict__ ell,
    float* __restrict__ partial)
{
    __shared__ float4 axial4[N_ELEM];    // 32 KiB: axial4[eid] = {s0,s1,s2,s3}
    __shared__ float red[MBLOCK / 64];   // 8

    const int b0 = blockIdx.x * S;
    const int t = threadIdx.x;

    // ---- phase 1: 8 independent dwordx4 loads (8 KiB/wave in flight) ----
    const float4* EA4 = (const float4*)(EA + (size_t)b0 * N_ELEM);
    const float4* e4  = (const float4*)(e  + (size_t)b0 * N_ELEM);
    float4 ea0 = EA4[0 * (N_ELEM / 4) + t];
    float4 ea1 = EA4[1 * (N_ELEM / 4) + t];
    float4 ea2 = EA4[2 * (N_ELEM / 4) + t];
    float4 ea3 = EA4[3 * (N_ELEM / 4) + t];
    float4 ee0 = e4 [0 * (N_ELEM / 4) + t];
    float4 ee1 = e4 [1 * (N_ELEM / 4) + t];
    float4 ee2 = e4 [2 * (N_ELEM / 4) + t];
    float4 ee3 = e4 [3 * (N_ELEM / 4) + t];

    // per-node counts (thread owns nodes t, t+512) — small L2-hit loads
    int c0 = min(cnt[t], SLOTS);
    int c1 = min(cnt[t + MBLOCK], SLOTS);
    int kmax = max(c0, c1);

    float4 p0, p1, p2, p3;               // p{s} = axial of sample s, elems 4t..4t+3
    p0.x = ea0.x * ee0.x; p0.y = ea0.y * ee0.y; p0.z = ea0.z * ee0.z; p0.w = ea0.w * ee0.w;
    p1.x = ea1.x * ee1.x; p1.y = ea1.y * ee1.y; p1.z = ea1.z * ee1.z; p1.w = ea1.w * ee1.w;
    p2.x = ea2.x * ee2.x; p2.y = ea2.y * ee2.y; p2.z = ea2.z * ee2.z; p2.w = ea2.w * ee2.w;
    p3.x = ea3.x * ee3.x; p3.y = ea3.y * ee3.y; p3.z = ea3.z * ee3.z; p3.w = ea3.w * ee3.w;

    // in-register transpose -> 4x ds_write_b128 (stride-64B: 2-way alias, free)
    axial4[4 * t + 0] = make_float4(p0.x, p1.x, p2.x, p3.x);
    axial4[4 * t + 1] = make_float4(p0.y, p1.y, p2.y, p3.y);
    axial4[4 * t + 2] = make_float4(p0.z, p1.z, p2.z, p3.z);
    axial4[4 * t + 3] = make_float4(p0.w, p1.w, p2.w, p3.w);

    __syncthreads();

    // ---- phase 2: gather, chunks of 2 ELL rows x 2 nodes ----
    float4 accx0 = make_float4(0.f, 0.f, 0.f, 0.f);
    float4 accy0 = make_float4(0.f, 0.f, 0.f, 0.f);
    float4 accx1 = make_float4(0.f, 0.f, 0.f, 0.f);
    float4 accy1 = make_float4(0.f, 0.f, 0.f, 0.f);

    for (int k0 = 0; k0 < kmax; k0 += 2) {               // k0+1 <= 31: in-bounds
        const float4* row = ell + (size_t)k0 * N_NODES;
        float4 pk00 = row[t];                            // row k0,   node t
        float4 pk01 = row[t + MBLOCK];                   // row k0,   node t+512
        float4 pk10 = row[N_NODES + t];                  // row k0+1, node t
        float4 pk11 = row[N_NODES + t + MBLOCK];         // row k0+1, node t+512
        float4 ax00 = axial4[__float_as_int(pk00.z)];
        float4 ax01 = axial4[__float_as_int(pk01.z)];
        float4 ax10 = axial4[__float_as_int(pk10.z)];
        float4 ax11 = axial4[__float_as_int(pk11.z)];
        FMA4(accx0, ax00, pk00.x);  FMA4(accy0, ax00, pk00.y);
        FMA4(accx1, ax01, pk01.x);  FMA4(accy1, ax01, pk01.y);
        FMA4(accx0, ax10, pk10.x);  FMA4(accy0, ax10, pk10.y);
        FMA4(accx1, ax11, pk11.x);  FMA4(accy1, ax11, pk11.y);
    }

    // ---- phase 3: residual & sum of squares; all 16 q/r loads hoisted ----
    const float2* q0 = (const float2*)(q + (size_t)(b0 + 0) * N_NODES * 2);
    const float2* q1 = (const float2*)(q + (size_t)(b0 + 1) * N_NODES * 2);
    const float2* q2 = (const float2*)(q + (size_t)(b0 + 2) * N_NODES * 2);
    const float2* q3 = (const float2*)(q + (size_t)(b0 + 3) * N_NODES * 2);
    const float2* r0 = (const float2*)(r + (size_t)(b0 + 0) * N_NODES * 2);
    const float2* r1 = (const float2*)(r + (size_t)(b0 + 1) * N_NODES * 2);
    const float2* r2 = (const float2*)(r + (size_t)(b0 + 2) * N_NODES * 2);
    const float2* r3 = (const float2*)(r + (size_t)(b0 + 3) * N_NODES * 2);

    float2 qa0 = q0[t];            float2 qa1 = q1[t];
    float2 qa2 = q2[t];            float2 qa3 = q3[t];
    float2 qb0 = q0[t + MBLOCK];   float2 qb1 = q1[t + MBLOCK];
    float2 qb2 = q2[t + MBLOCK];   float2 qb3 = q3[t + MBLOCK];
    float2 ra0 = r0[t];            float2 ra1 = r1[t];
    float2 ra2 = r2[t];            float2 ra3 = r3[t];
    float2 rb0 = r0[t + MBLOCK];   float2 rb1 = r1[t + MBLOCK];
    float2 rb2 = r2[t + MBLOCK];   float2 rb3 = r3[t + MBLOCK];

    float acc = 0.f;
    {
        float x, y;
        x = accx0.x - qa0.x - ra0.x;  y = accy0.x - qa0.y - ra0.y;  acc += x * x + y * y;
        x = accx0.y - qa1.x - ra1.x;  y = accy0.y - qa1.y - ra1.y;  acc += x * x + y * y;
        x = accx0.z - qa2.x - ra2.x;  y = accy0.z - qa2.y - ra2.y;  acc += x * x + y * y;
        x = accx0.w - qa3.x - ra3.x;  y = accy0.w - qa3.y - ra3.y;  acc += x * x + y * y;
        x = accx1.x - qb0.x - rb0.x;  y = accy1.x - qb0.y - rb0.y;  acc += x * x + y * y;
        x = accx1.y - qb1.x - rb1.x;  y = accy1.y - qb1.y - rb1.y;  acc += x * x + y * y;
        x = accx1.z - qb2.x - rb2.x;  y = accy1.z - qb2.y - rb2.y;  acc += x * x + y * y;
        x = accx1.w - qb3.x - rb3.x;  y = accy1.w - qb3.y - rb3.y;  acc += x * x + y * y;
    }

    // ---- wave + block reduce ----
#pragma unroll
    for (int off = 32; off > 0; off >>= 1)
        acc += __shfl_down(acc, off, 64);
    if ((t & 63) == 0) red[t >> 6] = acc;
    __syncthreads();
    if (t == 0) {
        float s = 0.f;
#pragma unroll
        for (int w = 0; w < MBLOCK / 64; ++w) s += red[w];
        partial[blockIdx.x] = s;
    }
}

// Reduce the per-block partials and apply the mean scale.
__global__ __launch_bounds__(1024) void neq_reduce_kernel(
    const float* __restrict__ partial, float* __restrict__ out)
{
    __shared__ float red[1024 / 64];
    const int t = threadIdx.x;
    float acc = partial[t];                              // MAIN_BLOCKS == 1024
#pragma unroll
    for (int off = 32; off > 0; off >>= 1)
        acc += __shfl_down(acc, off, 64);
    if ((t & 63) == 0) red[t >> 6] = acc;
    __syncthreads();
    if (t == 0) {
        float s = 0.f;
#pragma unroll
        for (int w = 0; w < 1024 / 64; ++w) s += red[w];
        const float inv_n = 1.0f / (float)((size_t)B_SAMPLES * N_NODES * 2);
        out[0] = s * inv_n;
    }
}

extern "C" void kernel_launch(void* const* d_in, const int* in_sizes, int n_in,
                              void* d_out, int out_size, void* d_ws, size_t ws_size,
                              hipStream_t stream) {
    const float* EA       = (const float*)d_in[0];
    const float* e        = (const float*)d_in[1];
    const float* q        = (const float*)d_in[2];
    const float* r        = (const float*)d_in[3];
    const float* vecs     = (const float*)d_in[4];
    const int*   node_ids = (const int*)d_in[5];
    const int*   elem_ids = (const int*)d_in[6];

    char* ws = (char*)d_ws;
    int*    cnt     = (int*)(ws + WS_CNT_OFF);
    float4* ell     = (float4*)(ws + WS_ELL_OFF);
    float*  partial = (float*)(ws + WS_PART_OFF);

    neq_zero_kernel<<<(SLOTS * N_NODES) / BLOCK, BLOCK, 0, stream>>>(ell, cnt);
    neq_build_kernel<<<E2 / BLOCK, BLOCK, 0, stream>>>(
        vecs, node_ids, elem_ids, cnt, ell);
    neq_main_kernel<<<MAIN_BLOCKS, MBLOCK, 0, stream>>>(
        EA, e, q, r, cnt, ell, partial);
    neq_reduce_kernel<<<1, 1024, 0, stream>>>(partial, (float*)d_out);
}

// Round 3
// 161.589 us; speedup vs baseline: 1.0422x; 1.0422x over previous
//
#include <hip/hip_runtime.h>

// Problem constants (from reference): B=4096, N_ELEM=2048, N_NODES=1024, E2=4096
#define B_SAMPLES 4096
#define N_ELEM    2048
#define N_NODES   1024
#define E2        4096
#define BLOCK     256                    // setup kernels
#define MBLOCK    512                    // main kernel block
#define SLOTS     32                     // max entries/node (Poisson mean 4; P(>=32) ~ 1e-15)
#define S         4                      // samples per main block
#define MAIN_BLOCKS (B_SAMPLES / S)      // 1024

// Workspace layout (bytes):
//   [0, 4K)        : cnt[N_NODES]          (int)
//   [4K, 4K+512K)  : ell[SLOTS][N_NODES]   (float4 {wx, wy, bitcast(eid), pad})
//   [4K+512K, ...) : partial[MAIN_BLOCKS]  (float)
#define WS_CNT_OFF   0
#define WS_ELL_OFF   4096
#define WS_PART_OFF  (4096 + SLOTS * N_NODES * 16)

// ---------------------------------------------------------------------------
// Setup A: zero ELL table + counters. 128 blocks x 256 = one float4 each.
// ---------------------------------------------------------------------------
__global__ __launch_bounds__(BLOCK) void neq_zero_kernel(
    float4* __restrict__ ell, int* __restrict__ cnt)
{
    const int i = blockIdx.x * BLOCK + threadIdx.x;      // 0 .. 32767
    ell[i] = make_float4(0.f, 0.f, 0.f, 0.f);
    if (i < N_NODES) cnt[i] = 0;
}

// ---------------------------------------------------------------------------
// Setup B: build transposed-ELL via global atomics (order-independent sum).
// ---------------------------------------------------------------------------
__global__ __launch_bounds__(BLOCK) void neq_build_kernel(
    const float* __restrict__ vecs, const int* __restrict__ node_ids,
    const int* __restrict__ elem_ids, int* __restrict__ cnt,
    float4* __restrict__ ell)
{
    const int j = blockIdx.x * BLOCK + threadIdx.x;      // 0 .. E2-1
    int nid = node_ids[j];
    int eid = elem_ids[j];
    float2 v = ((const float2*)vecs)[j];
    int slot = atomicAdd(&cnt[nid], 1);                  // device-scope
    if (slot < SLOTS) {
        ell[slot * N_NODES + nid] = make_float4(v.x, v.y, __int_as_float(eid), 0.f);
    }
}

// FMA of a float4 (per-sample) by a scalar weight into a float4 accumulator.
#define FMA4(A, V, W) do { (A).x += (V).x * (W); (A).y += (V).y * (W); \
                           (A).z += (V).z * (W); (A).w += (V).w * (W); } while (0)

// ---------------------------------------------------------------------------
// Main: one block (512 threads) per S=4 samples.
// R1 structure (phase 1 scalar-dword loads + stride-1 conflict-free float4
// LDS writes; phase 3 late q/r loads) + manually software-pipelined k-loop:
// each iteration issues the clamped prefetch of ELL rows k0+2/k0+3 BEFORE
// consuming rows k0/k0+1, so the 4 global loads are in flight under the
// dependent LDS gather + FMA chain. Zero-padded ELL rows make over-read
// rows contribute exactly 0; clamping keeps all addresses in-table.
// ---------------------------------------------------------------------------
__global__ __launch_bounds__(MBLOCK, 4) void neq_main_kernel(
    const float* __restrict__ EA, const float* __restrict__ e,
    const float* __restrict__ q,  const float* __restrict__ r,
    const int* __restrict__ cnt, const float4* __restrict__ ell,
    float* __restrict__ partial)
{
    __shared__ float4 axial4[N_ELEM];    // 32 KiB: axial4[eid] = {s0,s1,s2,s3}
    __shared__ float red[MBLOCK / 64];   // 8

    const int b0 = blockIdx.x * S;
    const int t = threadIdx.x;

    // ---- phase 1: axial4[eid] = EA*e for 4 samples (coalesced dword loads,
    //      conflict-free stride-1 ds_write_b128) ----
#pragma unroll
    for (int i = 0; i < N_ELEM / MBLOCK; ++i) {          // 4 iters
        int eid = t + i * MBLOCK;
        float4 p;
        const float* EAp = EA + (size_t)b0 * N_ELEM + eid;
        const float* ep  = e  + (size_t)b0 * N_ELEM + eid;
        p.x = EAp[0 * N_ELEM] * ep[0 * N_ELEM];
        p.y = EAp[1 * N_ELEM] * ep[1 * N_ELEM];
        p.z = EAp[2 * N_ELEM] * ep[2 * N_ELEM];
        p.w = EAp[3 * N_ELEM] * ep[3 * N_ELEM];
        axial4[eid] = p;
    }

    // per-node counts (thread owns nodes t, t+512)
    int c0n = min(cnt[t], SLOTS);
    int c1n = min(cnt[t + MBLOCK], SLOTS);
    int kmax = max(c0n, c1n);
    __syncthreads();

    // ---- phase 2: gather, 2 ELL rows x 2 nodes per iter, 1-deep prefetch ----
    float4 accx0 = make_float4(0.f, 0.f, 0.f, 0.f);
    float4 accy0 = make_float4(0.f, 0.f, 0.f, 0.f);
    float4 accx1 = make_float4(0.f, 0.f, 0.f, 0.f);
    float4 accy1 = make_float4(0.f, 0.f, 0.f, 0.f);

    // prologue: rows 0,1 for nodes t and t+512
    float4 c00 = ell[t];
    float4 c01 = ell[t + MBLOCK];
    float4 c10 = ell[N_NODES + t];
    float4 c11 = ell[N_NODES + t + MBLOCK];

    for (int k0 = 0; k0 < kmax; k0 += 2) {
        // prefetch rows k0+2, k0+3 (clamped: always in-table; padding rows = 0)
        int kp = k0 + 2;
        if (kp > SLOTS - 2) kp = SLOTS - 2;
        const float4* nrow = ell + (size_t)kp * N_NODES;
        float4 n00 = nrow[t];
        float4 n01 = nrow[t + MBLOCK];
        float4 n10 = nrow[N_NODES + t];
        float4 n11 = nrow[N_NODES + t + MBLOCK];

        // consume current rows (LDS gather + FMA) while prefetch is in flight
        float4 ax00 = axial4[__float_as_int(c00.z)];
        float4 ax01 = axial4[__float_as_int(c01.z)];
        float4 ax10 = axial4[__float_as_int(c10.z)];
        float4 ax11 = axial4[__float_as_int(c11.z)];
        FMA4(accx0, ax00, c00.x);  FMA4(accy0, ax00, c00.y);
        FMA4(accx1, ax01, c01.x);  FMA4(accy1, ax01, c01.y);
        FMA4(accx0, ax10, c10.x);  FMA4(accy0, ax10, c10.y);
        FMA4(accx1, ax11, c11.x);  FMA4(accy1, ax11, c11.y);

        // rotate
        c00 = n00; c01 = n01; c10 = n10; c11 = n11;
    }

    // ---- phase 3: residual & sum of squares (q/r loaded late: low pressure) ----
    float acc = 0.f;
#pragma unroll
    for (int s = 0; s < S; ++s) {
        const float2* q2 = (const float2*)(q + (size_t)(b0 + s) * N_NODES * 2);
        const float2* r2 = (const float2*)(r + (size_t)(b0 + s) * N_NODES * 2);
        float2 qa = q2[t];
        float2 ra = r2[t];
        float2 qb = q2[t + MBLOCK];
        float2 rb = r2[t + MBLOCK];
        float ax0 = (s == 0) ? accx0.x : (s == 1) ? accx0.y : (s == 2) ? accx0.z : accx0.w;
        float ay0 = (s == 0) ? accy0.x : (s == 1) ? accy0.y : (s == 2) ? accy0.z : accy0.w;
        float ax1 = (s == 0) ? accx1.x : (s == 1) ? accx1.y : (s == 2) ? accx1.z : accx1.w;
        float ay1 = (s == 0) ? accy1.x : (s == 1) ? accy1.y : (s == 2) ? accy1.z : accy1.w;
        float x = ax0 - qa.x - ra.x;
        float y = ay0 - qa.y - ra.y;
        acc += x * x + y * y;
        x = ax1 - qb.x - rb.x;
        y = ay1 - qb.y - rb.y;
        acc += x * x + y * y;
    }

    // ---- wave + block reduce ----
#pragma unroll
    for (int off = 32; off > 0; off >>= 1)
        acc += __shfl_down(acc, off, 64);
    if ((t & 63) == 0) red[t >> 6] = acc;
    __syncthreads();
    if (t == 0) {
        float s = 0.f;
#pragma unroll
        for (int w = 0; w < MBLOCK / 64; ++w) s += red[w];
        partial[blockIdx.x] = s;
    }
}

// Reduce the per-block partials and apply the mean scale.
__global__ __launch_bounds__(1024) void neq_reduce_kernel(
    const float* __restrict__ partial, float* __restrict__ out)
{
    __shared__ float red[1024 / 64];
    const int t = threadIdx.x;
    float acc = partial[t];                              // MAIN_BLOCKS == 1024
#pragma unroll
    for (int off = 32; off > 0; off >>= 1)
        acc += __shfl_down(acc, off, 64);
    if ((t & 63) == 0) red[t >> 6] = acc;
    __syncthreads();
    if (t == 0) {
        float s = 0.f;
#pragma unroll
        for (int w = 0; w < 1024 / 64; ++w) s += red[w];
        const float inv_n = 1.0f / (float)((size_t)B_SAMPLES * N_NODES * 2);
        out[0] = s * inv_n;
    }
}

extern "C" void kernel_launch(void* const* d_in, const int* in_sizes, int n_in,
                              void* d_out, int out_size, void* d_ws, size_t ws_size,
                              hipStream_t stream) {
    const float* EA       = (const float*)d_in[0];
    const float* e        = (const float*)d_in[1];
    const float* q        = (const float*)d_in[2];
    const float* r        = (const float*)d_in[3];
    const float* vecs     = (const float*)d_in[4];
    const int*   node_ids = (const int*)d_in[5];
    const int*   elem_ids = (const int*)d_in[6];

    char* ws = (char*)d_ws;
    int*    cnt     = (int*)(ws + WS_CNT_OFF);
    float4* ell     = (float4*)(ws + WS_ELL_OFF);
    float*  partial = (float*)(ws + WS_PART_OFF);

    neq_zero_kernel<<<(SLOTS * N_NODES) / BLOCK, BLOCK, 0, stream>>>(ell, cnt);
    neq_build_kernel<<<E2 / BLOCK, BLOCK, 0, stream>>>(
        vecs, node_ids, elem_ids, cnt, ell);
    neq_main_kernel<<<MAIN_BLOCKS, MBLOCK, 0, stream>>>(
        EA, e, q, r, cnt, ell, partial);
    neq_reduce_kernel<<<1, 1024, 0, stream>>>(partial, (float*)d_out);
}